// Round 8
// baseline (15.959 us; speedup 1.0000x reference)
//
#include <hip/hip_runtime.h>
#include <math.h>

#define Bn 4
#define Pn 24
#define Gn 24
#define Hd 512
#define Wd 512
#define NOBJ (Bn * Pn)
#define SPLIT 8
#define STEP (SPLIT * 256)     // groups per sweep
#define IOU_THRESH 0.5f

// ws layout:
//   acc float[NOBJ][SPLIT][4]  (bce_sum, inter, sum_p, sum_t)  -- every block
//     writes its slot unconditionally -> no zero-init, no atomics.
//   aux float[NOBJ][2]         (keep, cnt), written by part-0 block so the
//     finalize kernel needn't recompute the match.
#define AUX_OFF (NOBJ * SPLIT * 4)

__device__ __forceinline__ void proc_group(float4 p4, float4 q4, int rel, int Wr,
                                           float& v0, float& v1, float& v2, float& v3) {
    // per-pixel in-range mask: 0 <= rel+k < Wr (single unsigned cmp)
    bool m0 = (unsigned)(rel + 0) < (unsigned)Wr;
    bool m1 = (unsigned)(rel + 1) < (unsigned)Wr;
    bool m2 = (unsigned)(rel + 2) < (unsigned)Wr;
    bool m3 = (unsigned)(rel + 3) < (unsigned)Wr;
    float p0 = m0 ? p4.x : 0.0f, q0 = m0 ? q4.x : 0.0f;
    float p1 = m1 ? p4.y : 0.0f, q1 = m1 ? q4.y : 0.0f;
    float p2 = m2 ? p4.z : 0.0f, q2 = m2 ? q4.z : 0.0f;
    float p3 = m3 ? p4.w : 0.0f, q3 = m3 ? q4.w : 0.0f;
    // t exactly 0/1; masked pixel -> p=q=0 -> arg = 1 (log adds 0).
    // p in [1e-4, 1-1e-4] => -100 clamp provably inactive; 4-arg product
    // >= 1e-16 >> FLT_MIN: sum(log) == log(prod) -> ONE transcendental/group.
    float a0 = (q0 > 0.5f) ? p0 : 1.0f - p0;
    float a1 = (q1 > 0.5f) ? p1 : 1.0f - p1;
    float a2 = (q2 > 0.5f) ? p2 : 1.0f - p2;
    float a3 = (q3 > 0.5f) ? p3 : 1.0f - p3;
    v0 -= __logf((a0 * a1) * (a2 * a3));
    v1 = fmaf(p0, q0, fmaf(p1, q1, fmaf(p2, q2, fmaf(p3, q3, v1))));
    v2 += (p0 + p1) + (p2 + p3);
    v3 += (q0 + q1) + (q2 + q3);
}

__global__ __launch_bounds__(256) void region_kernel(
    const float* __restrict__ pred_masks, const float* __restrict__ gt_masks,
    const float* __restrict__ pred_boxes, const float* __restrict__ gt_boxes,
    const int* __restrict__ pred_valid, const int* __restrict__ gt_valid,
    float* __restrict__ acc, float* __restrict__ aux) {
    int obj = blockIdx.x;   // b*Pn + p
    int part = blockIdx.y;  // 0..SPLIT-1
    int b = obj / Pn;

    // ---- rectangle from pred box only (no match needed) ----
    const float* pbp = pred_boxes + (size_t)obj * 4;
    float A0 = pbp[0], A1 = pbp[1], A2 = pbp[2], A3 = pbp[3];
    // jnp.round is round-half-to-even -> rintf (default FE_TONEAREST)
    int y1 = max(0, (int)rintf(A0 * (float)Hd));
    int x1 = max(0, (int)rintf(A1 * (float)Wd));
    int y2 = min((int)rintf(A2 * (float)Hd), Hd - 1);
    int x2 = min((int)rintf(A3 * (float)Wd), Wd - 1);
    bool rect_ok = (y2 >= y1 && x2 >= x1);

    int Wr = 0, W4 = 0, N4 = 0, rel0 = 0;
    const float* pm = pred_masks + (size_t)obj * Hd * Wd;
    float4 pA, qA, pB, qB;
    int idxA = 0, idxB = 0, rA = 0, cA = 0, rB = 0, cB = 0;
    bool hasA = false, hasB = false;
    if (rect_ok) {
        Wr = x2 - x1 + 1;
        int Hr = y2 - y1 + 1;
        int x1a = x1 & ~3;                  // 16B-aligned start column
        W4 = (x2 >> 2) - (x1 >> 2) + 1;     // aligned groups covering [x1,x2]
        N4 = Hr * W4;
        rel0 = x1a - x1;                    // -3..0
        pm += x1a;
        idxA = part * 256 + (int)threadIdx.x;
        if (idxA < N4) {
            hasA = true;
            rA = idxA / W4;                 // one runtime div
            cA = idxA - rA * W4;
            // ISSUE p-loads NOW -- cold-HBM latency overlaps the IoU loop below
            pA = *reinterpret_cast<const float4*>(pm + (y1 + rA) * Wd + (cA << 2));
            idxB = idxA + STEP;
            if (idxB < N4) {
                hasB = true;
                int dS = STEP / W4, cS = STEP - (STEP / W4) * W4;
                rB = rA + dS; cB = cA + cS;
                if (cB >= W4) { cB -= W4; ++rB; }
                pB = *reinterpret_cast<const float4*>(pm + (y1 + rB) * Wd + (cB << 2));
            }
        }
    }

    // ---- IoU match (gt_boxes loads overlap the in-flight p-loads) ----
    float area_a = (A2 - A0) * (A3 - A1);
    float best = -1.0f;
    int gidx = 0;
    #pragma unroll
    for (int g = 0; g < Gn; ++g) {
        const float* gb = gt_boxes + ((size_t)b * Gn + g) * 4;
        float b0 = gb[0], b1 = gb[1], b2 = gb[2], b3 = gb[3];
        float area_b = (b2 - b0) * (b3 - b1);
        float ih = fmaxf(fminf(A2, b2) - fmaxf(A0, b0), 0.0f);
        float iw = fmaxf(fminf(A3, b3) - fmaxf(A1, b1), 0.0f);
        float inter = ih * iw;
        float uni = area_a + area_b - inter;
        float iou = (uni == 0.0f) ? 0.0f : inter / uni;
        if (gt_valid[b * Gn + g] == 0) iou = -1.0f;
        if (iou > best) { best = iou; gidx = g; }  // first-max == jnp.argmax
    }
    int keep = (best >= IOU_THRESH) && (pred_valid[obj] != 0);

    float v0 = 0.0f, v1 = 0.0f, v2 = 0.0f, v3 = 0.0f;
    if (keep && hasA) {
        const float* gm = gt_masks + ((size_t)b * Gn + gidx) * Hd * Wd + ((x1 & ~3));
        // q-loads for the first pair (need gidx)
        qA = *reinterpret_cast<const float4*>(gm + (y1 + rA) * Wd + (cA << 2));
        if (hasB)
            qB = *reinterpret_cast<const float4*>(gm + (y1 + rB) * Wd + (cB << 2));
        const int S2 = 2 * STEP;
        int dr2 = S2 / W4, dc2 = S2 - (S2 / W4) * W4;
        while (true) {
            // ---- prefetch next pair (addresses independent of current data) ----
            int idxA2 = idxA + S2;
            bool hasA2 = idxA2 < N4;       // hasA2 implies hasB (ordering)
            bool hasB2 = false;
            float4 pA2, qA2, pB2, qB2;
            int rA2 = rA, cA2 = cA, rB2 = rB, cB2 = cB;
            if (hasA2) {
                cA2 = cA + dc2; rA2 = rA + dr2;
                if (cA2 >= W4) { cA2 -= W4; ++rA2; }
                int off = (y1 + rA2) * Wd + (cA2 << 2);
                pA2 = *reinterpret_cast<const float4*>(pm + off);
                qA2 = *reinterpret_cast<const float4*>(gm + off);
                int idxB2 = idxB + S2;
                if (idxB2 < N4) {
                    hasB2 = true;
                    cB2 = cB + dc2; rB2 = rB + dr2;
                    if (cB2 >= W4) { cB2 -= W4; ++rB2; }
                    int offb = (y1 + rB2) * Wd + (cB2 << 2);
                    pB2 = *reinterpret_cast<const float4*>(pm + offb);
                    qB2 = *reinterpret_cast<const float4*>(gm + offb);
                }
            }
            // ---- process current pair ----
            proc_group(pA, qA, rel0 + (cA << 2), Wr, v0, v1, v2, v3);
            if (hasB)
                proc_group(pB, qB, rel0 + (cB << 2), Wr, v0, v1, v2, v3);
            if (!hasA2) break;
            idxA = idxA2; idxB = idxB + S2;
            rA = rA2; cA = cA2; rB = rB2; cB = cB2;
            pA = pA2; qA = qA2; pB = pB2; qB = qB2;
            hasB = hasB2;
        }
    }

    // ---- block reduce 256 -> 4 sums ----
    for (int o = 32; o > 0; o >>= 1) {
        v0 += __shfl_down(v0, o, 64);
        v1 += __shfl_down(v1, o, 64);
        v2 += __shfl_down(v2, o, 64);
        v3 += __shfl_down(v3, o, 64);
    }
    __shared__ float red[4][4];
    int lane = threadIdx.x & 63, w = threadIdx.x >> 6;
    if (lane == 0) { red[w][0] = v0; red[w][1] = v1; red[w][2] = v2; red[w][3] = v3; }
    __syncthreads();
    if (threadIdx.x < 4) {
        float sfin = red[0][threadIdx.x] + red[1][threadIdx.x] +
                     red[2][threadIdx.x] + red[3][threadIdx.x];
        acc[((size_t)obj * SPLIT + part) * 4 + threadIdx.x] = sfin;  // unconditional slot write
    } else if (part == 0 && threadIdx.x == 4) {
        float cnt = rect_ok ? (float)((y2 - y1 + 1) * (x2 - x1 + 1)) : 0.0f;
        aux[obj * 2 + 0] = keep ? 1.0f : 0.0f;
        aux[obj * 2 + 1] = cnt;
    }
}

__global__ __launch_bounds__(128) void finalize_kernel(
    const float* __restrict__ acc, const float* __restrict__ aux,
    float* __restrict__ out) {
    int i = threadIdx.x;  // 128 threads, 2 waves
    float loss = 0.0f, nk = 0.0f;
    if (i < NOBJ) {
        float keepf = aux[i * 2 + 0];
        float cnt = aux[i * 2 + 1];
        if (keepf > 0.5f) {
            nk = 1.0f;
            const float4* a = reinterpret_cast<const float4*>(acc) + (size_t)i * SPLIT;
            float s0 = 0.0f, s1 = 0.0f, s2 = 0.0f, s3 = 0.0f;
            #pragma unroll
            for (int p = 0; p < SPLIT; ++p) {
                float4 v = a[p];
                s0 += v.x; s1 += v.y; s2 += v.z; s3 += v.w;
            }
            float bce = s0 / fmaxf(cnt, 1.0f);
            float dice = 1.0f - (2.0f * s1 + 1.0f) / (s2 + s3 + 1.0f);
            loss = bce + dice;
        }
    }
    float v0 = loss, v1 = nk;
    for (int o = 32; o > 0; o >>= 1) {
        v0 += __shfl_down(v0, o, 64);
        v1 += __shfl_down(v1, o, 64);
    }
    __shared__ float red[2][2];
    if ((threadIdx.x & 63) == 0) { red[threadIdx.x >> 6][0] = v0; red[threadIdx.x >> 6][1] = v1; }
    __syncthreads();
    if (threadIdx.x == 0) {
        float total = red[0][0] + red[1][0];
        float nobj = red[0][1] + red[1][1];
        out[0] = total / fmaxf(nobj, 1.0f);
    }
}

extern "C" void kernel_launch(void* const* d_in, const int* in_sizes, int n_in,
                              void* d_out, int out_size, void* d_ws, size_t ws_size,
                              hipStream_t stream) {
    const float* pred_masks = (const float*)d_in[0];
    const float* pred_boxes = (const float*)d_in[1];
    const float* gt_boxes   = (const float*)d_in[2];
    const float* gt_masks   = (const float*)d_in[3];
    const int*   pred_valid = (const int*)d_in[4];
    const int*   gt_valid   = (const int*)d_in[5];
    float* out = (float*)d_out;
    float* acc = (float*)d_ws;       // [NOBJ][SPLIT][4]
    float* aux = acc + AUX_OFF;      // [NOBJ][2]

    region_kernel<<<dim3(NOBJ, SPLIT), 256, 0, stream>>>(
        pred_masks, gt_masks, pred_boxes, gt_boxes, pred_valid, gt_valid, acc, aux);
    finalize_kernel<<<1, 128, 0, stream>>>(acc, aux, out);
}